// Round 2
// baseline (451.394 us; speedup 1.0000x reference)
//
#include <hip/hip_runtime.h>

// SpiralConv conv block: per-channel complex first-order recurrence
//   h[n] = c*h[n-1] + x[n],  h[-1] = last_conv_init[d],  out = Re(h)*x
// with c_d = exp(-exp(lmlg_d)) * e^{i*theta_d}.
//
// R6: single-dispatch decoupled-lookback scan. R5's two-dispatch scheme read
// x twice (128 MiB vs 64 MiB ideal) and paid two device-wide ramps; per-kernel
// times fell below the harness's 41us ws-poison fill, so the remaining cost is
// structural. Now: one kernel, x read once into registers, per-chunk partial
// summaries + opportunistic inclusive prefixes published with device-scope
// flags, atomic-ticket block ordering for deadlock-free lookback.

#define L_   4096
#define B_   4
#define D_   1024
#define BD_  (B_ * D_)        // 4096 floats per time step
#define NC_  128              // chunks
#define CH_  (L_ / NC_)       // 32 steps per chunk
#define NBLK_ (NC_ * B_ * 4)  // 2048 blocks: (k, b, 256-channel slice db)
#define SUMN_ ((size_t)NC_ * B_ * D_)   // float2 entries per summary array

// ws layout (bytes):
//   [0]        uint ticket
//   [256)      uint flags[NBLK_]   (0=none, 1=partial, 2=inclusive)
//   [16384)    float2 part[SUMN_]  (per-chunk local summaries, immutable)
//   [+4MiB)    float2 incl[SUMN_]  (inclusive prefixes, immutable)
#define WS_FLAGS_OFF  64          // in uints
#define WS_SUM_OFF    16384       // in bytes
#define WS_BYTES_NEEDED (WS_SUM_OFF + 2u * SUMN_ * sizeof(float2))

// ------------------------------------------------------------- init --------
__global__ __launch_bounds__(256) void sc_init(unsigned int* wsu) {
  // zero ticket + flags (first 16 KiB)
  for (int i = threadIdx.x; i < 4096; i += 256) wsu[i] = 0u;
}

// ------------------------------------------------------------- fused -------
__global__ __launch_bounds__(256) void sc_fused(
    const float* __restrict__ x,
    const float* __restrict__ lmlg,
    const float* __restrict__ theta,
    const float* __restrict__ init,
    unsigned int* __restrict__ wsu,
    float* __restrict__ out) {
  __shared__ int s_blk;
  __shared__ int s_m;

  unsigned int* ticket = wsu;
  unsigned int* flags  = wsu + WS_FLAGS_OFF;
  float2* part = (float2*)((char*)wsu + WS_SUM_OFF);
  float2* incl = part + SUMN_;

  // ticket: chunk ids assigned in actual start order -> any block we spin on
  // has already started and never waits on a later ticket => no deadlock.
  if (threadIdx.x == 0)
    s_blk = (int)__hip_atomic_fetch_add(ticket, 1u, __ATOMIC_RELAXED,
                                        __HIP_MEMORY_SCOPE_AGENT);
  __syncthreads();
  const int blk = s_blk;
  const int db  = blk & 3;
  const int b   = (blk >> 2) & 3;
  const int k   = blk >> 4;
  const int t   = threadIdx.x;
  const int d   = (db << 8) + t;

  // per-channel decay*rotation and chunk jump factor C = c^CH_
  const float lg = lmlg[d], th = theta[d];
  const float e  = expf(lg);
  const float g  = expf(-e);
  const float cr = g * cosf(th), ci = g * sinf(th);
  const float chf = (float)CH_;
  const float G  = expf(-e * chf);
  const float Cr = G * cosf(th * chf), Ci = G * sinf(th * chf);

  // ---- load x chunk into registers; local scan from zero state ----
  const size_t off = (size_t)k * CH_ * BD_ + (size_t)b * D_ + d;
  const float* xp = x + off;
  float xv[CH_];
  float sr = 0.f, si = 0.f;
#pragma unroll
  for (int j = 0; j < CH_; ++j) {
    xv[j] = xp[(size_t)j * BD_];
    float nr = fmaf(cr, sr, fmaf(-ci, si, xv[j]));
    float ni = fmaf(cr, si, ci * sr);
    sr = nr; si = ni;
  }

  // ---- publish partial ----
  const size_t sidx = (size_t)(k * B_ + b) * D_ + d;
  part[sidx] = make_float2(sr, si);
  __syncthreads();
  if (t == 0) {
    __threadfence();  // release:部 writes visible device-wide before flag
    __hip_atomic_store(&flags[blk], 1u, __ATOMIC_RELEASE,
                       __HIP_MEMORY_SCOPE_AGENT);
  }

  // ---- lookback: scan down consuming partials until an inclusive ----
  if (t == 0) {
    int m = -1;
    for (int kk = k - 1; kk >= 0; --kk) {
      const int fidx = (kk << 4) | (b << 2) | db;
      unsigned int f;
      while ((f = __hip_atomic_load(&flags[fidx], __ATOMIC_RELAXED,
                                    __HIP_MEMORY_SCOPE_AGENT)) == 0u)
        __builtin_amdgcn_s_sleep(8);
      if (f >= 2u) { m = kk; break; }
    }
    s_m = m;
    __threadfence();  // acquire side: invalidate caches before block reads
  }
  __syncthreads();
  const int m = s_m;

  // carry into chunk k:
  //   H_k = sum_{j=m+1}^{k-1} C^{k-1-j} * part[j]
  //         + C^{k-1-m} * incl[m]          (m >= 0)
  //         + C^{k}     * (init, 0)        (m == -1)
  float hr, hi;
  {
    float ar = 0.f, ai = 0.f;   // accumulated sum
    float pr = 1.f, pi = 0.f;   // Cpow = C^{k-1-kk} entering iteration kk
    for (int kk = k - 1; kk > m; --kk) {
      float2 s = part[(size_t)(kk * B_ + b) * D_ + d];
      ar = fmaf(pr, s.x, fmaf(-pi, s.y, ar));
      ai = fmaf(pr, s.y, fmaf( pi, s.x, ai));
      float npr = fmaf(pr, Cr, -pi * Ci);
      float npi = fmaf(pr, Ci,  pi * Cr);
      pr = npr; pi = npi;
    }
    if (m >= 0) {
      float2 I = incl[(size_t)(m * B_ + b) * D_ + d];
      ar = fmaf(pr, I.x, fmaf(-pi, I.y, ar));
      ai = fmaf(pr, I.y, fmaf( pi, I.x, ai));
    } else {
      float iv = init[d];
      ar = fmaf(pr, iv, ar);
      ai = fmaf(pi, iv, ai);
    }
    hr = ar; hi = ai;
  }

  // ---- publish inclusive I_k = C*H_k + s_k (unblocks successors early) ----
  {
    float Ir = fmaf(Cr, hr, fmaf(-Ci, hi, sr));
    float Ii = fmaf(Cr, hi, fmaf( Ci, hr, si));
    incl[sidx] = make_float2(Ir, Ii);
  }
  __syncthreads();
  if (t == 0) {
    __threadfence();
    __hip_atomic_store(&flags[blk], 2u, __ATOMIC_RELEASE,
                       __HIP_MEMORY_SCOPE_AGENT);
  }

  // ---- replay recurrence from registers with carry; write out ----
  float* op = out + off;
#pragma unroll
  for (int j = 0; j < CH_; ++j) {
    float nr = fmaf(cr, hr, fmaf(-ci, hi, xv[j]));
    float ni = fmaf(cr, hi, ci * hr);
    hr = nr; hi = ni;
    op[(size_t)j * BD_] = nr * xv[j];
  }
}

// ------------------------------------------------------------- fallback ----
// ws-free fully sequential per-column scan (used only if ws_size is tiny).
__global__ __launch_bounds__(256) void sc_full(
    const float* __restrict__ x, const float* __restrict__ lmlg,
    const float* __restrict__ theta, const float* __restrict__ init,
    float* __restrict__ out) {
  const int idx = blockIdx.x * 256 + threadIdx.x;   // column b*D+d
  const int d   = idx & (D_ - 1);
  float g = expf(-expf(lmlg[d]));
  float cr = g * cosf(theta[d]), ci = g * sinf(theta[d]);
  float hr = init[d], hi = 0.f;
  const float* xp = x + idx;
  float*       op = out + idx;
  for (int n = 0; n < L_; ++n) {
    float xv = xp[(size_t)n * BD_];
    float nr = fmaf(cr, hr, fmaf(-ci, hi, xv));
    float ni = fmaf(cr, hi, ci * hr);
    hr = nr; hi = ni;
    op[(size_t)n * BD_] = nr * xv;
  }
}

// ---------------------------------------------------------------------------
extern "C" void kernel_launch(void* const* d_in, const int* in_sizes, int n_in,
                              void* d_out, int out_size, void* d_ws, size_t ws_size,
                              hipStream_t stream) {
  const float* x     = (const float*)d_in[0];
  const float* lmlg  = (const float*)d_in[1];
  const float* theta = (const float*)d_in[2];
  const float* init  = (const float*)d_in[3];
  float* out = (float*)d_out;

  if (ws_size >= (size_t)WS_BYTES_NEEDED) {
    unsigned int* wsu = (unsigned int*)d_ws;
    sc_init <<<1, 256, 0, stream>>>(wsu);
    sc_fused<<<NBLK_, 256, 0, stream>>>(x, lmlg, theta, init, wsu, out);
  } else {
    sc_full<<<BD_ / 256, 256, 0, stream>>>(x, lmlg, theta, init, out);
  }
}

// Round 3
// 134.316 us; speedup vs baseline: 3.3607x; 3.3607x over previous
//
#include <hip/hip_runtime.h>

// SpiralConv conv block: per-channel complex first-order recurrence
//   h[n] = c*h[n-1] + x[n],  h[-1] = last_conv_init[d],  out = Re(h)*x
// with c_d = exp(-exp(lmlg_d)) * e^{i*theta_d}.
//
// R7: revert to R5's two-dispatch chunked scan (135 us measured; the R6
// fused decoupled-lookback ran 389 us: agent-scope fences serialize on
// non-coherent per-XCD L2s, and VGPR=36 showed the register x-buffer never
// materialized). Squeeze the kernels instead:
//   - compile-time CH=32 (full address precompute, batched loads)
//   - nontemporal out stores (streaming; keep x hot in L2/L3 for reads)
//   - C^2-jump unrolled carry scan (halves the serial chain)
// Grid stays 2048 blocks x 256 thr = 8192 waves = 100% wave slots.

#define L_  4096
#define B_  4
#define D_  1024
#define BD_ (B_ * D_)      // 4096 floats per time step
#define NC_ 128
#define CH_ (L_ / NC_)     // 32

// ---------------------------------------------------------------- K1 -------
// One block per (chunk k, batch b, 256-channel slice db); 1 channel/thread.
// Chunk summary s = recurrence over CH steps from zero state.
template <int CH>
__global__ __launch_bounds__(256) void sc_sum(
    const float* __restrict__ x,
    const float* __restrict__ lmlg,
    const float* __restrict__ theta,
    float2* __restrict__ ws) {
  const int t   = threadIdx.x;
  const int bid = blockIdx.x;
  const int db  = bid & 3;               // D/256 = 4 slices
  const int b   = (bid >> 2) & (B_ - 1);
  const int k   = bid >> 4;              // 16 blocks per chunk
  const int d   = (db << 8) + t;

  const float lg = lmlg[d], th = theta[d];
  const float g  = expf(-expf(lg));
  const float cr = g * cosf(th), ci = g * sinf(th);

  float sr = 0.f, si = 0.f;
  const float* xp = x + (size_t)k * CH * BD_ + (size_t)b * D_ + d;
#pragma unroll 8
  for (int j = 0; j < CH; ++j) {
    float xv = xp[(size_t)j * BD_];
    float nr = fmaf(cr, sr, fmaf(-ci, si, xv));
    float ni = fmaf(cr, si, ci * sr);
    sr = nr; si = ni;
  }
  ws[(size_t)(k * B_ + b) * D_ + d] = make_float2(sr, si);
}

// ---------------------------------------------------------------- K2 -------
// Same decomposition. Prefix-scan summaries 0..k-1 (L2/L3-hot, 4 MiB buffer)
// with C^2 jumps, then replay the per-step recurrence over x (L3-hot after
// K1) and stream out = Re(h)*x with nontemporal stores.
template <int CH>
__global__ __launch_bounds__(256) void sc_out(
    const float* __restrict__ x,
    const float* __restrict__ lmlg,
    const float* __restrict__ theta,
    const float* __restrict__ init,
    const float2* __restrict__ ws,
    float* __restrict__ out) {
  const int t   = threadIdx.x;
  const int bid = blockIdx.x;
  const int db  = bid & 3;
  const int b   = (bid >> 2) & (B_ - 1);
  const int k   = bid >> 4;
  const int d   = (db << 8) + t;

  const float lg = lmlg[d], th = theta[d];
  const float e  = expf(lg);
  const float g  = expf(-e);
  const float cr = g * cosf(th), ci = g * sinf(th);

  // jump factor C = c^CH (from params; matches prior rounds' numerics)
  const float chf = (float)CH;
  const float G   = expf(-e * chf);
  const float Cr  = G * cosf(th * chf), Ci = G * sinf(th * chf);

  // carry into chunk k: h = init; for kk<k: h = C*h + s[kk]
  // processed two-at-a-time: h = C2*h + (C*s[kk] + s[kk+1])
  float hr = init[d], hi = 0.f;
  const float2* sp = ws + (size_t)b * D_ + d;
  {
    const float C2r = fmaf(Cr, Cr, -Ci * Ci);
    const float C2i = 2.f * Cr * Ci;
    int kk = 0;
    for (; kk + 2 <= k; kk += 2) {
      float2 s0 = sp[(size_t)kk * BD_];
      float2 s1 = sp[(size_t)(kk + 1) * BD_];
      // u = C*s0 + s1
      float ur = fmaf(Cr, s0.x, fmaf(-Ci, s0.y, s1.x));
      float ui = fmaf(Cr, s0.y, fmaf( Ci, s0.x, s1.y));
      float nr = fmaf(C2r, hr, fmaf(-C2i, hi, ur));
      float ni = fmaf(C2r, hi, fmaf( C2i, hr, ui));
      hr = nr; hi = ni;
    }
    if (kk < k) {
      float2 s = sp[(size_t)kk * BD_];
      float nr = fmaf(Cr, hr, fmaf(-Ci, hi, s.x));
      float ni = fmaf(Cr, hi, fmaf( Ci, hr, s.y));
      hr = nr; hi = ni;
    }
  }

  // replay recurrence over this chunk, stream out = Re(h)*x
  const size_t off = (size_t)k * CH * BD_ + (size_t)b * D_ + d;
  const float* xp = x + off;
  float*       op = out + off;
#pragma unroll 8
  for (int j = 0; j < CH; ++j) {
    float xv = xp[(size_t)j * BD_];
    float nr = fmaf(cr, hr, fmaf(-ci, hi, xv));
    float ni = fmaf(cr, hi, ci * hr);
    hr = nr; hi = ni;
    __builtin_nontemporal_store(nr * xv, op + (size_t)j * BD_);
  }
}

// ------------------------------------------------------------- fallback ----
// ws-free fully sequential per-column scan (used only if ws_size is tiny).
__global__ __launch_bounds__(256) void sc_full(
    const float* __restrict__ x, const float* __restrict__ lmlg,
    const float* __restrict__ theta, const float* __restrict__ init,
    float* __restrict__ out) {
  const int idx = blockIdx.x * 256 + threadIdx.x;   // column b*D+d
  const int d   = idx & (D_ - 1);
  float g = expf(-expf(lmlg[d]));
  float cr = g * cosf(theta[d]), ci = g * sinf(theta[d]);
  float hr = init[d], hi = 0.f;
  const float* xp = x + idx;
  float*       op = out + idx;
  for (int n = 0; n < L_; ++n) {
    float xv = xp[(size_t)n * BD_];
    float nr = fmaf(cr, hr, fmaf(-ci, hi, xv));
    float ni = fmaf(cr, hi, ci * hr);
    hr = nr; hi = ni;
    op[(size_t)n * BD_] = nr * xv;
  }
}

// ---------------------------------------------------------------------------
extern "C" void kernel_launch(void* const* d_in, const int* in_sizes, int n_in,
                              void* d_out, int out_size, void* d_ws, size_t ws_size,
                              hipStream_t stream) {
  const float* x     = (const float*)d_in[0];
  const float* lmlg  = (const float*)d_in[1];
  const float* theta = (const float*)d_in[2];
  const float* init  = (const float*)d_in[3];
  float*  out = (float*)d_out;
  float2* ws  = (float2*)d_ws;

  const size_t need = (size_t)NC_ * B_ * D_ * sizeof(float2);   // 4 MiB
  if (ws_size >= need) {
    const int grid = NC_ * B_ * (D_ / 256);   // 2048 blocks
    sc_sum<CH_><<<grid, 256, 0, stream>>>(x, lmlg, theta, ws);
    sc_out<CH_><<<grid, 256, 0, stream>>>(x, lmlg, theta, init, ws, out);
  } else {
    sc_full<<<BD_ / 256, 256, 0, stream>>>(x, lmlg, theta, init, out);
  }
}